// Round 4
// baseline (121.883 us; speedup 1.0000x reference)
//
#include <hip/hip_runtime.h>
#include <cstdint>

#define NN 4096
#define FF 512

typedef short bf16x8 __attribute__((ext_vector_type(8)));
typedef float f32x16 __attribute__((ext_vector_type(16)));

__device__ __forceinline__ uint16_t f2bf(float f) {
    uint32_t u = __builtin_bit_cast(uint32_t, f);
    u += 0x7FFFu + ((u >> 16) & 1u);   // round-to-nearest-even
    return (uint16_t)(u >> 16);
}

// ---------------------------------------------------------------------------
// k_prep: Abf[i][j] = bf16(adj[i][j] + (i==j)), d_i = rsqrt(1 + rowsum(adj))
// (d scaling now applied in GEMM epilogue (rows) and k_zt (cols))
// ---------------------------------------------------------------------------
__global__ __launch_bounds__(256) void k_prep(const float* __restrict__ adj,
                                              float* __restrict__ d,
                                              uint16_t* __restrict__ Abf) {
    const int row  = blockIdx.x * 4 + (threadIdx.x >> 6);
    const int lane = threadIdx.x & 63;
    const float4* p = (const float4*)(adj + (size_t)row * NN);
    float4 v[16];
    float s = 0.f;
#pragma unroll
    for (int i = 0; i < 16; ++i) {
        v[i] = p[lane + i * 64];
        s += (v[i].x + v[i].y) + (v[i].z + v[i].w);
    }
#pragma unroll
    for (int off = 1; off < 64; off <<= 1) s += __shfl_xor(s, off);
    const float di = rsqrtf(s + 1.0f);
    if (lane == 0) d[row] = di;
    uint16_t* outp = Abf + (size_t)row * NN;
#pragma unroll
    for (int i = 0; i < 16; ++i) {
        const int cb = (lane + i * 64) * 4;
        float a0 = v[i].x, a1 = v[i].y, a2 = v[i].z, a3 = v[i].w;
        if (cb + 0 == row) a0 += 1.0f;
        if (cb + 1 == row) a1 += 1.0f;
        if (cb + 2 == row) a2 += 1.0f;
        if (cb + 3 == row) a3 += 1.0f;
        ushort4 o;
        o.x = f2bf(a0); o.y = f2bf(a1); o.z = f2bf(a2); o.w = f2bf(a3);
        *(ushort4*)(outp + cb) = o;
    }
}

// ---------------------------------------------------------------------------
// k_xc: x f32 -> bf16 (row-major, K-contiguous already)
// ---------------------------------------------------------------------------
__global__ __launch_bounds__(256) void k_xc(const float* __restrict__ x,
                                            uint16_t* __restrict__ xbf) {
    const size_t t4 = (size_t)blockIdx.x * 256 + threadIdx.x;
    float4 v = *(const float4*)(x + t4 * 4);
    ushort4 o;
    o.x = f2bf(v.x); o.y = f2bf(v.y); o.z = f2bf(v.z); o.w = f2bf(v.w);
    *(ushort4*)(xbf + t4 * 4) = o;
}

// ---------------------------------------------------------------------------
// k_wc: W f32 -> bf16
// ---------------------------------------------------------------------------
__global__ __launch_bounds__(256) void k_wc(const float* __restrict__ W,
                                            uint16_t* __restrict__ Wbf) {
    const size_t t4 = (size_t)blockIdx.x * 256 + threadIdx.x;
    float4 v = *(const float4*)(W + t4 * 4);
    ushort4 o;
    o.x = f2bf(v.x); o.y = f2bf(v.y); o.z = f2bf(v.z); o.w = f2bf(v.w);
    *(ushort4*)(Wbf + t4 * 4) = o;
}

// ---------------------------------------------------------------------------
// k_zt: zdT[n][k] = bf16(d[k] * z32[k][n])   (transpose+scale, via LDS)
// ---------------------------------------------------------------------------
__global__ __launch_bounds__(256) void k_zt(const float* __restrict__ z32,
                                            const float* __restrict__ d,
                                            uint16_t* __restrict__ zdT) {
    __shared__ uint16_t t[64][72];
    const int k0 = blockIdx.x * 64;
    const int n0 = blockIdx.y * 64;
    const int tid = threadIdx.x;
    const int r   = tid >> 4;
    const int c4  = tid & 15;
#pragma unroll
    for (int pass = 0; pass < 4; ++pass) {
        const int row = pass * 16 + r;
        float4 v = *(const float4*)(z32 + (size_t)(k0 + row) * FF + n0 + c4 * 4);
        const float dk = d[k0 + row];
        t[c4 * 4 + 0][row] = f2bf(v.x * dk);
        t[c4 * 4 + 1][row] = f2bf(v.y * dk);
        t[c4 * 4 + 2][row] = f2bf(v.z * dk);
        t[c4 * 4 + 3][row] = f2bf(v.w * dk);
    }
    __syncthreads();
#pragma unroll
    for (int pass = 0; pass < 2; ++pass) {
        const int cid = pass * 256 + tid;
        const int n  = cid >> 3;
        const int ch = cid & 7;
        *(uint4*)(zdT + (size_t)(n0 + n) * NN + k0 + ch * 8) = *(const uint4*)&t[n][ch * 8];
    }
}

// ---------------------------------------------------------------------------
// k_mm: C[4096][512](+)= A[4096][K] * Bt[512][K]^T   (bf16 operands)
// 512 threads = 8 waves (2x4). 32x32x16 MFMA. BK=32, 4-buffer LDS ring,
// stage-first, counted vmcnt (never 0 in main loop). Split-K via f32 atomics.
// MODE 0: plain atomicAdd.  MODE 2: val = d[row]*acc (+bias if ks==0), atomicAdd.
// Chunk swizzle: slot q holds global chunk (q - (row>>1))&3; read slot
// s = (cl + (row>>1))&3  -> reaches the 4-lane/bank-group b128 floor.
// ---------------------------------------------------------------------------
template <int BM, int BN, int K, int SPLITK, int MODE>
__global__ __launch_bounds__(512, 2) void k_mm(const uint16_t* __restrict__ A,
                                               const uint16_t* __restrict__ Bt,
                                               const float* __restrict__ bias,
                                               const float* __restrict__ dvec,
                                               float* __restrict__ outf) {
    constexpr int MT    = NN / BM;
    constexpr int NTC   = FF / BN;
    constexpr int KSLEN = K / SPLITK;
    constexpr int NT    = KSLEN / 32;     // ktiles of BK=32
    constexpr int MTX   = MT / 8;
    constexpr int MF    = BM / 64;        // frags along m per wave
    constexpr int NF    = BN / 128;       // frags along n per wave
    constexpr int LPT_A = BM / 128;       // gload_lds per thread per tile (A)
    constexpr int LPT_B = BN / 128;
    constexpr int LPT   = LPT_A + LPT_B;

    __shared__ uint16_t As[4][BM * 32];
    __shared__ uint16_t Bs[4][BN * 32];

    // XCD-grouped decode: id&7 = XCD; all split/n blocks of an m-stripe share L2
    const int id   = blockIdx.x;
    const int slot = id >> 3;
    const int mt   = (id & 7) * MTX + slot / (NTC * SPLITK);
    const int rem  = slot % (NTC * SPLITK);
    const int nt   = rem % NTC;
    const int ks   = rem / NTC;
    const int m0 = mt * BM;
    const int n0 = nt * BN;
    const int k0 = ks * KSLEN;

    const int tid  = threadIdx.x;
    const int w    = tid >> 6;
    const int lane = tid & 63;
    const int wm = w >> 2, wn = w & 3;

    f32x16 acc[MF][NF] = {};

    auto STAGE = [&](int t, int buf) {
        const int ktb = k0 + t * 32;
#pragma unroll
        for (int i = 0; i < LPT_A; ++i) {
            const int boff = i * 8192 + tid * 16;
            const int row  = boff >> 6;
            const int q    = (boff >> 4) & 3;
            const int c    = (q + 4 - ((row >> 1) & 3)) & 3;
            const uint16_t* src = A + (size_t)(m0 + row) * K + ktb + c * 8;
            __builtin_amdgcn_global_load_lds(
                (const __attribute__((address_space(1))) void*)src,
                (__attribute__((address_space(3))) void*)&As[buf][boff >> 1],
                16, 0, 0);
        }
#pragma unroll
        for (int i = 0; i < LPT_B; ++i) {
            const int boff = i * 8192 + tid * 16;
            const int row  = boff >> 6;
            const int q    = (boff >> 4) & 3;
            const int c    = (q + 4 - ((row >> 1) & 3)) & 3;
            const uint16_t* src = Bt + (size_t)(n0 + row) * K + ktb + c * 8;
            __builtin_amdgcn_global_load_lds(
                (const __attribute__((address_space(1))) void*)src,
                (__attribute__((address_space(3))) void*)&Bs[buf][boff >> 1],
                16, 0, 0);
        }
    };

    auto COMPUTE = [&](int buf) {
#pragma unroll
        for (int ksl = 0; ksl < 2; ++ksl) {
            const int cl = ksl * 2 + (lane >> 5);
            bf16x8 af[MF], bfr[NF];
#pragma unroll
            for (int mf = 0; mf < MF; ++mf) {
                const int r = wm * (BM / 2) + mf * 32 + (lane & 31);
                const int s = (cl + ((r >> 1) & 3)) & 3;
                af[mf] = *(const bf16x8*)&As[buf][r * 32 + s * 8];
            }
#pragma unroll
            for (int nf = 0; nf < NF; ++nf) {
                const int r = wn * (BN / 4) + nf * 32 + (lane & 31);
                const int s = (cl + ((r >> 1) & 3)) & 3;
                bfr[nf] = *(const bf16x8*)&Bs[buf][r * 32 + s * 8];
            }
#pragma unroll
            for (int mf = 0; mf < MF; ++mf)
#pragma unroll
                for (int nf = 0; nf < NF; ++nf)
                    acc[mf][nf] = __builtin_amdgcn_mfma_f32_32x32x16_bf16(
                        af[mf], bfr[nf], acc[mf][nf], 0, 0, 0);
        }
    };

    // prologue: 3 tiles in flight
    STAGE(0, 0);
    STAGE(1, 1);
    STAGE(2, 2);

    // main loop: stage-first, wait own tile-t loads (3*LPT left in flight),
    // barrier (others' loads covered by their own wait+barrier), compute.
    for (int t = 0; t < NT - 3; ++t) {
        STAGE(t + 3, (t + 3) & 3);
        if constexpr (LPT == 4) asm volatile("s_waitcnt vmcnt(12)" ::: "memory");
        else                    asm volatile("s_waitcnt vmcnt(6)" ::: "memory");
        __builtin_amdgcn_s_barrier();
        COMPUTE(t & 3);
        __builtin_amdgcn_s_barrier();   // buf (t+4)&3 == t&3 overwritten next iter
    }
    // tail: drain 2*LPT -> LPT -> 0
    if constexpr (LPT == 4) asm volatile("s_waitcnt vmcnt(8)" ::: "memory");
    else                    asm volatile("s_waitcnt vmcnt(4)" ::: "memory");
    __builtin_amdgcn_s_barrier();
    COMPUTE((NT - 3) & 3);
    if constexpr (LPT == 4) asm volatile("s_waitcnt vmcnt(4)" ::: "memory");
    else                    asm volatile("s_waitcnt vmcnt(2)" ::: "memory");
    __builtin_amdgcn_s_barrier();
    COMPUTE((NT - 2) & 3);
    asm volatile("s_waitcnt vmcnt(0)" ::: "memory");
    __builtin_amdgcn_s_barrier();
    COMPUTE((NT - 1) & 3);

    // epilogue: C/D 32x32 layout col=lane&31, row=(r&3)+8*(r>>2)+4*(lane>>5)
    const int rb = m0 + wm * (BM / 2) + ((lane >> 5) << 2);
    const int cb = n0 + wn * (BN / 4) + (lane & 31);
#pragma unroll
    for (int mf = 0; mf < MF; ++mf) {
#pragma unroll
        for (int nf = 0; nf < NF; ++nf) {
            const int gcol = cb + nf * 32;
            float bv = 0.f;
            if constexpr (MODE == 2) { if (ks == 0) bv = bias[gcol]; }
#pragma unroll
            for (int r = 0; r < 16; ++r) {
                const int grow = rb + mf * 32 + (r & 3) + ((r >> 2) << 3);
                float v = acc[mf][nf][r];
                if constexpr (MODE == 2) v = v * dvec[grow] + bv;
                unsafeAtomicAdd(&outf[(size_t)grow * FF + gcol], v);
            }
        }
    }
}

// ---------------------------------------------------------------------------
extern "C" void kernel_launch(void* const* d_in, const int* in_sizes, int n_in,
                              void* d_out, int out_size, void* d_ws, size_t ws_size,
                              hipStream_t stream) {
    const float* x   = (const float*)d_in[0];   // [4096][512]
    const float* adj = (const float*)d_in[1];   // [4096][4096]
    const float* W   = (const float*)d_in[2];   // [512][512]
    const float* b   = (const float*)d_in[3];   // [512]
    float* out = (float*)d_out;                 // [4096][512] f32

    char* ws = (char*)d_ws;
    float*    d_   = (float*)ws;                                  // 16 KB (pad 64K)
    uint16_t* Abf  = (uint16_t*)(ws + 65536);                     // 32 MB
    uint16_t* zdT  = Abf + (size_t)NN * NN;                       // 4 MB
    uint16_t* xbf  = zdT + (size_t)FF * NN;                       // 4 MB
    uint16_t* Wbf  = xbf + (size_t)NN * FF;                       // 0.5 MB
    float*    z32  = (float*)(Wbf + (size_t)FF * FF);             // 8 MB

    hipMemsetAsync(z32, 0, (size_t)NN * FF * sizeof(float), stream);
    hipMemsetAsync(out, 0, (size_t)NN * FF * sizeof(float), stream);
    k_wc<<<FF * FF / 1024, 256, 0, stream>>>(W, Wbf);
    k_xc<<<NN * FF / 1024, 256, 0, stream>>>(x, xbf);
    k_prep<<<NN / 4, 256, 0, stream>>>(adj, d_, Abf);
    // z = x @ W^T  (split-K=2, atomics into z32)
    k_mm<128, 128, FF, 2, 0><<<256, 512, 0, stream>>>(xbf, Wbf, nullptr, nullptr, z32);
    // zdT[n][k] = d_k * z[k][n] in bf16
    k_zt<<<dim3(NN / 64, FF / 64), 256, 0, stream>>>(z32, d_, zdT);
    // out = D * (A @ zdT^T) + b  (split-K=8, d-scale + bias fused, atomics)
    k_mm<256, 256, NN, 8, 2><<<256, 512, 0, stream>>>(Abf, zdT, b, d_, out);
}

// Round 5
// 71.192 us; speedup vs baseline: 1.7120x; 1.7120x over previous
//
#include <hip/hip_runtime.h>
#include <cstdint>

#define NN 4096
#define FF 512

typedef short bf16x8 __attribute__((ext_vector_type(8)));
typedef float f32x16 __attribute__((ext_vector_type(16)));

__device__ __forceinline__ uint16_t f2bf(float f) {
    uint32_t u = __builtin_bit_cast(uint32_t, f);
    u += 0x7FFFu + ((u >> 16) & 1u);   // round-to-nearest-even
    return (uint16_t)(u >> 16);
}

// ---------------------------------------------------------------------------
// k_prep: Abf[i][j] = bf16(adj[i][j] + (i==j)), d_i = rsqrt(1 + rowsum(adj))
// (row scale d_i applied in k_red; col scale d_j folded into zdT)
// ---------------------------------------------------------------------------
__global__ __launch_bounds__(256) void k_prep(const float* __restrict__ adj,
                                              float* __restrict__ d,
                                              uint16_t* __restrict__ Abf) {
    const int row  = blockIdx.x * 4 + (threadIdx.x >> 6);
    const int lane = threadIdx.x & 63;
    const float4* p = (const float4*)(adj + (size_t)row * NN);
    float4 v[16];
    float s = 0.f;
#pragma unroll
    for (int i = 0; i < 16; ++i) {
        v[i] = p[lane + i * 64];
        s += (v[i].x + v[i].y) + (v[i].z + v[i].w);
    }
#pragma unroll
    for (int off = 1; off < 64; off <<= 1) s += __shfl_xor(s, off);
    const float di = rsqrtf(s + 1.0f);
    if (lane == 0) d[row] = di;
    uint16_t* outp = Abf + (size_t)row * NN;
#pragma unroll
    for (int i = 0; i < 16; ++i) {
        const int cb = (lane + i * 64) * 4;
        float a0 = v[i].x, a1 = v[i].y, a2 = v[i].z, a3 = v[i].w;
        if (cb + 0 == row) a0 += 1.0f;
        if (cb + 1 == row) a1 += 1.0f;
        if (cb + 2 == row) a2 += 1.0f;
        if (cb + 3 == row) a3 += 1.0f;
        ushort4 o;
        o.x = f2bf(a0); o.y = f2bf(a1); o.z = f2bf(a2); o.w = f2bf(a3);
        *(ushort4*)(outp + cb) = o;
    }
}

// ---------------------------------------------------------------------------
// k_xc / k_wc: f32 -> bf16 casts
// ---------------------------------------------------------------------------
__global__ __launch_bounds__(256) void k_xc(const float* __restrict__ x,
                                            uint16_t* __restrict__ xbf) {
    const size_t t4 = (size_t)blockIdx.x * 256 + threadIdx.x;
    float4 v = *(const float4*)(x + t4 * 4);
    ushort4 o;
    o.x = f2bf(v.x); o.y = f2bf(v.y); o.z = f2bf(v.z); o.w = f2bf(v.w);
    *(ushort4*)(xbf + t4 * 4) = o;
}

__global__ __launch_bounds__(256) void k_wc(const float* __restrict__ W,
                                            uint16_t* __restrict__ Wbf) {
    const size_t t4 = (size_t)blockIdx.x * 256 + threadIdx.x;
    float4 v = *(const float4*)(W + t4 * 4);
    ushort4 o;
    o.x = f2bf(v.x); o.y = f2bf(v.y); o.z = f2bf(v.z); o.w = f2bf(v.w);
    *(ushort4*)(Wbf + t4 * 4) = o;
}

// ---------------------------------------------------------------------------
// k_zt: zdT[n][k] = bf16(d[k] * z32[k][n])   (transpose+scale, via LDS)
// ---------------------------------------------------------------------------
__global__ __launch_bounds__(256) void k_zt(const float* __restrict__ z32,
                                            const float* __restrict__ d,
                                            uint16_t* __restrict__ zdT) {
    __shared__ uint16_t t[64][72];
    const int k0 = blockIdx.x * 64;
    const int n0 = blockIdx.y * 64;
    const int tid = threadIdx.x;
    const int r   = tid >> 4;
    const int c4  = tid & 15;
#pragma unroll
    for (int pass = 0; pass < 4; ++pass) {
        const int row = pass * 16 + r;
        float4 v = *(const float4*)(z32 + (size_t)(k0 + row) * FF + n0 + c4 * 4);
        const float dk = d[k0 + row];
        t[c4 * 4 + 0][row] = f2bf(v.x * dk);
        t[c4 * 4 + 1][row] = f2bf(v.y * dk);
        t[c4 * 4 + 2][row] = f2bf(v.z * dk);
        t[c4 * 4 + 3][row] = f2bf(v.w * dk);
    }
    __syncthreads();
#pragma unroll
    for (int pass = 0; pass < 2; ++pass) {
        const int cid = pass * 256 + tid;
        const int n  = cid >> 3;
        const int ch = cid & 7;
        *(uint4*)(zdT + (size_t)(n0 + n) * NN + k0 + ch * 8) = *(const uint4*)&t[n][ch * 8];
    }
}

// ---------------------------------------------------------------------------
// k_mm: outp[ks] [4096][512] = A[4096][K-slice] * Bt[512][K-slice]^T  (bf16)
// 512 threads = 8 waves (4m x 2n). 32x32x16 MFMA, MF=BM/128, NF=BN/64 per wave
// -> LDS-pipe (MF+NF b128/kslice) balanced against MFMA-pipe (MF*NF).
// BK=64, double-buffered LDS, gload_lds w16, counted vmcnt (never 0 in loop).
// 8-slot XOR chunk swizzle (source-side inverse + read-side) [R3-verified].
// Plain f32 stores; split-K partials reduced by k_red (deterministic).
// ---------------------------------------------------------------------------
template <int BM, int BN, int K, int SPLITK>
__global__ __launch_bounds__(512, 2) void k_mm(const uint16_t* __restrict__ A,
                                               const uint16_t* __restrict__ Bt,
                                               float* __restrict__ outp) {
    constexpr int MT    = NN / BM;
    constexpr int NTC   = FF / BN;
    constexpr int KSLEN = K / SPLITK;
    constexpr int NT    = KSLEN / 64;
    constexpr int MTX   = MT / 8;
    constexpr int MF    = BM / 128;   // frags along m per wave (4 m-waves)
    constexpr int NF    = BN / 64;    // frags along n per wave (2 n-waves)
    constexpr int LPT_A = BM / 64;    // gload_lds per thread per tile
    constexpr int LPT_B = BN / 64;
    constexpr int LPT   = LPT_A + LPT_B;

    __shared__ uint16_t As[2][BM * 64];
    __shared__ uint16_t Bs[2][BN * 64];

    // XCD-grouped decode: id&7 = XCD; all (nt,ks) blocks of an m-stripe
    // run concurrently on one XCD -> A stripe stays L2-resident.
    const int id   = blockIdx.x;
    const int slot = id >> 3;
    const int mt   = (id & 7) * MTX + slot / (NTC * SPLITK);
    const int rem  = slot % (NTC * SPLITK);
    const int nt   = rem % NTC;
    const int ks   = rem / NTC;
    const int m0 = mt * BM;
    const int n0 = nt * BN;
    const int k0 = ks * KSLEN;

    const int tid  = threadIdx.x;
    const int w    = tid >> 6;
    const int lane = tid & 63;
    const int wm = w >> 1, wn = w & 1;

    f32x16 acc[MF][NF] = {};

    auto STAGE = [&](int t, int buf) {
        const int ktb = k0 + t * 64;
#pragma unroll
        for (int i = 0; i < LPT_A; ++i) {
            const int boff = i * 8192 + tid * 16;
            const int row  = boff >> 7;          // 128 B rows
            const int q    = (boff >> 4) & 7;    // LDS chunk slot
            const int c    = q ^ (row & 7);      // global chunk held there
            const uint16_t* src = A + (size_t)(m0 + row) * K + ktb + c * 8;
            __builtin_amdgcn_global_load_lds(
                (const __attribute__((address_space(1))) void*)src,
                (__attribute__((address_space(3))) void*)&As[buf][boff >> 1],
                16, 0, 0);
        }
#pragma unroll
        for (int i = 0; i < LPT_B; ++i) {
            const int boff = i * 8192 + tid * 16;
            const int row  = boff >> 7;
            const int q    = (boff >> 4) & 7;
            const int c    = q ^ (row & 7);
            const uint16_t* src = Bt + (size_t)(n0 + row) * K + ktb + c * 8;
            __builtin_amdgcn_global_load_lds(
                (const __attribute__((address_space(1))) void*)src,
                (__attribute__((address_space(3))) void*)&Bs[buf][boff >> 1],
                16, 0, 0);
        }
    };

    auto COMPUTE = [&](int buf) {
#pragma unroll
        for (int ksl = 0; ksl < 4; ++ksl) {
            const int cl = ksl * 2 + (lane >> 5);    // k-chunk 0..7
            bf16x8 af[MF], bfr[NF];
#pragma unroll
            for (int mf = 0; mf < MF; ++mf) {
                const int r = wm * (MF * 32) + mf * 32 + (lane & 31);
                af[mf] = *(const bf16x8*)&As[buf][r * 64 + ((cl ^ (r & 7)) << 3)];
            }
#pragma unroll
            for (int nf = 0; nf < NF; ++nf) {
                const int r = wn * (NF * 32) + nf * 32 + (lane & 31);
                bfr[nf] = *(const bf16x8*)&Bs[buf][r * 64 + ((cl ^ (r & 7)) << 3)];
            }
#pragma unroll
            for (int mf = 0; mf < MF; ++mf)
#pragma unroll
                for (int nf = 0; nf < NF; ++nf)
                    acc[mf][nf] = __builtin_amdgcn_mfma_f32_32x32x16_bf16(
                        af[mf], bfr[nf], acc[mf][nf], 0, 0, 0);
        }
    };

    STAGE(0, 0);
    for (int t = 0; t < NT - 1; ++t) {
        STAGE(t + 1, (t + 1) & 1);
        if constexpr (LPT == 6) asm volatile("s_waitcnt vmcnt(6)" ::: "memory");
        else                    asm volatile("s_waitcnt vmcnt(3)" ::: "memory");
        __builtin_amdgcn_s_barrier();
        COMPUTE(t & 1);
        __builtin_amdgcn_s_barrier();
    }
    asm volatile("s_waitcnt vmcnt(0)" ::: "memory");
    __builtin_amdgcn_s_barrier();
    COMPUTE((NT - 1) & 1);

    // epilogue: plain f32 stores; C/D 32x32: col=lane&31, row=(r&3)+8*(r>>2)+4*(lane>>5)
    float* dst = outp + (size_t)ks * NN * FF;
    const int rb = m0 + wm * (MF * 32) + ((lane >> 5) << 2);
    const int cb = n0 + wn * (NF * 32) + (lane & 31);
#pragma unroll
    for (int mf = 0; mf < MF; ++mf) {
#pragma unroll
        for (int nf = 0; nf < NF; ++nf) {
            const int gcol = cb + nf * 32;
#pragma unroll
            for (int r = 0; r < 16; ++r) {
                const int grow = rb + mf * 32 + (r & 3) + ((r >> 2) << 3);
                dst[(size_t)grow * FF + gcol] = acc[mf][nf][r];
            }
        }
    }
}

// ---------------------------------------------------------------------------
// k_red: out[i][j] = d[i] * (p0+p1+p2+p3)[i][j] + b[j]
// ---------------------------------------------------------------------------
__global__ __launch_bounds__(256) void k_red(const float* __restrict__ parts,
                                             const float* __restrict__ d,
                                             const float* __restrict__ b,
                                             float* __restrict__ out) {
    constexpr size_t STRIDE = (size_t)NN * FF;
    const size_t g   = (size_t)blockIdx.x * 256 + threadIdx.x;   // float4 id
    const int    row = (int)((g * 4) >> 9);
    const int    col = (int)((g * 4) & 511);
    float4 s = *(const float4*)(parts + g * 4);
#pragma unroll
    for (int p = 1; p < 4; ++p) {
        float4 v = *(const float4*)(parts + p * STRIDE + g * 4);
        s.x += v.x; s.y += v.y; s.z += v.z; s.w += v.w;
    }
    const float di = d[row];
    const float4 bv = *(const float4*)(b + col);
    float4 o;
    o.x = s.x * di + bv.x;
    o.y = s.y * di + bv.y;
    o.z = s.z * di + bv.z;
    o.w = s.w * di + bv.w;
    *(float4*)(out + g * 4) = o;
}

// ---------------------------------------------------------------------------
extern "C" void kernel_launch(void* const* d_in, const int* in_sizes, int n_in,
                              void* d_out, int out_size, void* d_ws, size_t ws_size,
                              hipStream_t stream) {
    const float* x   = (const float*)d_in[0];   // [4096][512]
    const float* adj = (const float*)d_in[1];   // [4096][4096]
    const float* W   = (const float*)d_in[2];   // [512][512]
    const float* b   = (const float*)d_in[3];   // [512]
    float* out = (float*)d_out;                 // [4096][512] f32

    char* ws = (char*)d_ws;
    float*    d_    = (float*)ws;                                 // 16 KB (pad 64K)
    uint16_t* Abf   = (uint16_t*)(ws + 65536);                    // 32 MB
    uint16_t* zdT   = Abf + (size_t)NN * NN;                      // 4 MB
    uint16_t* xbf   = zdT + (size_t)FF * NN;                      // 4 MB
    uint16_t* Wbf   = xbf + (size_t)NN * FF;                      // 0.5 MB
    float*    z32   = (float*)(Wbf + (size_t)FF * FF);            // 8 MB
    float*    parts = z32 + (size_t)NN * FF;                      // 32 MB (4 x 8MB)

    k_wc<<<FF * FF / 1024, 256, 0, stream>>>(W, Wbf);
    k_xc<<<NN * FF / 1024, 256, 0, stream>>>(x, xbf);
    k_prep<<<NN / 4, 256, 0, stream>>>(adj, d_, Abf);
    // z = x @ W^T  (plain stores, no split)
    k_mm<128, 64, FF, 1><<<256, 512, 0, stream>>>(xbf, Wbf, z32);
    // zdT[n][k] = d_k * z[k][n] in bf16
    k_zt<<<dim3(NN / 64, FF / 64), 256, 0, stream>>>(z32, d_, zdT);
    // parts[ks] = A @ zdT^T (k-slice ks), plain stores
    k_mm<256, 128, NN, 4><<<256, 512, 0, stream>>>(Abf, zdT, parts);
    // out = d[i] * sum(parts) + b
    k_red<<<NN * FF / 1024, 256, 0, stream>>>(parts, d_, b, out);
}